// Round 9
// baseline (149.341 us; speedup 1.0000x reference)
//
#include <hip/hip_runtime.h>

// pyramid_roi_align (Mask R-CNN), MI355X.
// R10: R9's SCH=2 rewrite of the pipeline core failed correctness (absmax 4.1,
// bug not locatable by inspection) -> rule: never rework the proven core and
// the geometry in one step. R10 keeps R8's fast_steps VERBATIM (SCH=4, 4
// steps, counted vmcnt {1,3,5,7}, reg epilogue -- harness-proven at 44us) and
// changes ONLY geometry: 64-thread 1-wave blocks, grid N*16 (fine granularity
// lifts measured avg occupancy toward the 10-wave LDS cap; R8's 2-wave blocks
// averaged 5.3 of cap 10), fallback rewritten as a 64-lane R3-style gather
// loop, and n = bid % N (1000 % 8 == 0 -> all 16 chunks of a box on one XCD).

#define POOL 7
#define NCH  256
#define ELEMS_PER_BOX (NCH * POOL * POOL)    // 12544
#define WCH 16                               // channels per block (1 wave)
#define SCH 4                                // channels per batch/step
#define NSTEPS 4
#define ROWS 14                              // 2 rows (y0,y1) per py
#define MAXG 7                               // max GLD instrs per batch
#define BUFSLOT (MAXG * 64)                  // 448 f4 slots per buffer (7168 B)
#define STEPOUT (SCH * 49)                   // 196 outputs per step
#define BLKOUT (WCH * 49)                    // 784 outputs per block

typedef float f2 __attribute__((ext_vector_type(2)));
typedef __attribute__((address_space(1))) const void* gas_ptr;
typedef __attribute__((address_space(3))) void*       las_ptr;

#define VMWAIT(n) asm volatile("s_waitcnt vmcnt(" #n ")" ::: "memory")

template<int S4S>
__device__ __forceinline__ void fast_steps(
    const float* __restrict__ lvl, float* __restrict__ opw,
    float* __restrict__ buf0, float* __restrict__ buf1,
    const int lane, const int HW, const unsigned cb0, const unsigned lim,
    const int xb0, const int* s_rowoff, const int* s_dx,
    const float* s_a, const float* s_b, const float* s_w0, const float* s_w1)
{
    constexpr int G   = (56 * S4S + 63) / 64;   // GLDs per batch: 1,3,5,7
    constexpr int S   = 4 * S4S;                // LDS row stride (floats)
    constexpr int NSL = 56 * S4S;               // live f4 slots per batch

    // ---- slot metadata (channel-relative float offsets), named scalars ----
    unsigned inv0 = 0x40000000u, inv1 = 0x40000000u, inv2 = 0x40000000u,
             inv3 = 0x40000000u, inv4 = 0x40000000u, inv5 = 0x40000000u,
             inv6 = 0x40000000u;
#define SLOTMETA(k, var)                                                      \
    if constexpr ((k) < G) {                                                  \
        const int idx = (k) * 64 + lane;                                      \
        if (idx < NSL) {                                                      \
            const int rid = idx / S4S;          /* const div */               \
            const int q   = idx - rid * S4S;                                  \
            const int cl  = rid / 14;                                         \
            const int r   = rid - 14 * cl;                                    \
            var = (unsigned)(cl * HW + s_rowoff[r] + xb0 + 4 * q);            \
        }                                                                     \
    }
    SLOTMETA(0, inv0) SLOTMETA(1, inv1) SLOTMETA(2, inv2) SLOTMETA(3, inv3)
    SLOTMETA(4, inv4) SLOTMETA(5, inv5) SLOTMETA(6, inv6)
#undef SLOTMETA

    // ---- cell metadata (4 output slots/step), named scalars ----
    int   to0, to1, to2, to3;
    float aa0, bb0, w00, w10, aa1, bb1, w01, w11;
    float aa2, bb2, w02, w12, aa3, bb3, w03, w13;
#define CELLMETA(j, tov, aav, bbv, w0v, w1v)                                  \
    { int oidx = (j) * 64 + lane;                                             \
      oidx = oidx < STEPOUT ? oidx : STEPOUT - 1;                             \
      const int cc = oidx / 49;                                               \
      const int pp = oidx - 49 * cc;                                          \
      tov = (cc * ROWS + 2 * (pp / 7)) * S + s_dx[pp];                        \
      aav = s_a[pp]; bbv = s_b[pp]; w0v = s_w0[pp]; w1v = s_w1[pp]; }
    CELLMETA(0, to0, aa0, bb0, w00, w10)
    CELLMETA(1, to1, aa1, bb1, w01, w11)
    CELLMETA(2, to2, aa2, bb2, w02, w12)
    CELLMETA(3, to3, aa3, bb3, w03, w13)
#undef CELLMETA

#define GLD1(k, var, so, bp)                                                  \
    if constexpr ((k) < G) {                                                  \
        unsigned o_ = (so) + var; o_ = o_ > lim ? lim : o_;                   \
        __builtin_amdgcn_global_load_lds((gas_ptr)(lvl + o_),                 \
            (las_ptr)((bp) + ((k) * 64 + lane) * 4), 16, 0, 0);               \
    }
#define ISSUE(t, bp)                                                          \
    { const unsigned so_ = cb0 + (unsigned)((t) * SCH * HW);                  \
      GLD1(0, inv0, so_, bp) GLD1(1, inv1, so_, bp) GLD1(2, inv2, so_, bp)    \
      GLD1(3, inv3, so_, bp) GLD1(4, inv4, so_, bp) GLD1(5, inv5, so_, bp)    \
      GLD1(6, inv6, so_, bp) }
#define CELLC(bp, tov, aav, bbv, w0v, w1v, rvar)                              \
    { const float t00 = (bp)[tov],     t01 = (bp)[tov + 1];                   \
      const float t10 = (bp)[tov + S], t11 = (bp)[tov + S + 1];               \
      rvar = (t00 * aav + t01 * bbv) * w0v + (t10 * aav + t11 * bbv) * w1v; }
#define VMWAIT_G                                                              \
    if constexpr (G == 1) { VMWAIT(1); }                                      \
    else if constexpr (G == 3) { VMWAIT(3); }                                 \
    else if constexpr (G == 5) { VMWAIT(5); }                                 \
    else { VMWAIT(7); }

    float r00, r01, r02, r03, r10, r11, r12, r13;
    float r20, r21, r22, r23, r30, r31, r32, r33;

    // prologue: two batches in flight
    ISSUE(0, buf0)
    ISSUE(1, buf1)

    // step 0: wait b0 (b1 stays in flight), compute, refill buf0 with b2
    VMWAIT_G;
    __builtin_amdgcn_sched_barrier(0);
    CELLC(buf0, to0, aa0, bb0, w00, w10, r00)
    CELLC(buf0, to1, aa1, bb1, w01, w11, r01)
    CELLC(buf0, to2, aa2, bb2, w02, w12, r02)
    CELLC(buf0, to3, aa3, bb3, w03, w13, r03)
    asm volatile("s_waitcnt lgkmcnt(0)" ::: "memory");   // reads retired
    __builtin_amdgcn_sched_barrier(0);
    ISSUE(2, buf0)

    // step 1
    VMWAIT_G;
    __builtin_amdgcn_sched_barrier(0);
    CELLC(buf1, to0, aa0, bb0, w00, w10, r10)
    CELLC(buf1, to1, aa1, bb1, w01, w11, r11)
    CELLC(buf1, to2, aa2, bb2, w02, w12, r12)
    CELLC(buf1, to3, aa3, bb3, w03, w13, r13)
    asm volatile("s_waitcnt lgkmcnt(0)" ::: "memory");
    __builtin_amdgcn_sched_barrier(0);
    ISSUE(3, buf1)

    // step 2 (b3 stays in flight)
    VMWAIT_G;
    __builtin_amdgcn_sched_barrier(0);
    CELLC(buf0, to0, aa0, bb0, w00, w10, r20)
    CELLC(buf0, to1, aa1, bb1, w01, w11, r21)
    CELLC(buf0, to2, aa2, bb2, w02, w12, r22)
    CELLC(buf0, to3, aa3, bb3, w03, w13, r23)

    // step 3: final drain
    VMWAIT(0);
    __builtin_amdgcn_sched_barrier(0);
    CELLC(buf1, to0, aa0, bb0, w00, w10, r30)
    CELLC(buf1, to1, aa1, bb1, w01, w11, r31)
    CELLC(buf1, to2, aa2, bb2, w02, w12, r32)
    CELLC(buf1, to3, aa3, bb3, w03, w13, r33)

    // epilogue: coalesced stores (196 outputs/step = 3*64 + 4)
    const bool tail = (lane < STEPOUT - 192);
    opw[0 * STEPOUT +   0 + lane] = r00;
    opw[0 * STEPOUT +  64 + lane] = r01;
    opw[0 * STEPOUT + 128 + lane] = r02;
    if (tail) opw[0 * STEPOUT + 192 + lane] = r03;
    opw[1 * STEPOUT +   0 + lane] = r10;
    opw[1 * STEPOUT +  64 + lane] = r11;
    opw[1 * STEPOUT + 128 + lane] = r12;
    if (tail) opw[1 * STEPOUT + 192 + lane] = r13;
    opw[2 * STEPOUT +   0 + lane] = r20;
    opw[2 * STEPOUT +  64 + lane] = r21;
    opw[2 * STEPOUT + 128 + lane] = r22;
    if (tail) opw[2 * STEPOUT + 192 + lane] = r23;
    opw[3 * STEPOUT +   0 + lane] = r30;
    opw[3 * STEPOUT +  64 + lane] = r31;
    opw[3 * STEPOUT + 128 + lane] = r32;
    if (tail) opw[3 * STEPOUT + 192 + lane] = r33;

#undef GLD1
#undef ISSUE
#undef CELLC
#undef VMWAIT_G
}

__global__ __launch_bounds__(64, 2) void roi_align_kernel(
    const float* __restrict__ boxes,
    const float* __restrict__ p2, const float* __restrict__ p3,
    const float* __restrict__ p4, const float* __restrict__ p5,
    float* __restrict__ out, int N)
{
    const int bid       = blockIdx.x;
    const int n         = bid % N;   // box; chunks N apart (1000%8==0 -> same XCD)
    const int sixteenth = bid / N;   // channel 16-block [16s, 16s+16)

    __shared__ float s_stage[2][BUFSLOT * 4];     // 14336 B (1 wave, dbuf)
    __shared__ float s_a[49], s_b[49], s_w0[49], s_w1[49];
    __shared__ int   s_dx[49];
    __shared__ int   s_off0[49], s_off1[49];      // fallback gather offsets
    __shared__ int   s_rowoff[ROWS];
    __shared__ int   s_HW, s_xb0, s_sel;
    __shared__ const float* s_fmap;

    const int tid = threadIdx.x;

    if (tid < 49) {
        const float by1 = boxes[4 * n + 0];
        const float bx1 = boxes[4 * n + 1];
        const float by2 = boxes[4 * n + 2];
        const float bx2 = boxes[4 * n + 3];
        const float h = by2 - by1;
        const float w = bx2 - bx1;
        float rl = 4.0f + log2f(sqrtf(h * w) / 0.21875f);
        int level = (int)rintf(rl);            // round-half-even = jnp.round
        level = min(5, max(2, level));
        const int H = 256 >> (level - 2);
        const int W = H;
        const int py = tid / 7;
        const int px = tid - 7 * py;

        // y interp
        const float ty = (float)py / 6.0f;
        const float ys = (by1 + ty * (by2 - by1)) * (float)(H - 1);
        const float yf = floorf(ys);
        const float ly = ys - yf;
        int y0 = (int)yf; y0 = min(H - 1, max(0, y0));
        const int y1 = min(H - 1, y0 + 1);
        const float vy = (ys >= 0.0f && ys <= (float)(H - 1)) ? 1.0f : 0.0f;

        // x interp
        const float tx = (float)px / 6.0f;
        const float xs = (bx1 + tx * (bx2 - bx1)) * (float)(W - 1);
        const float xf = floorf(xs);
        const float lx = xs - xf;
        int x0 = (int)xf; x0 = min(W - 1, max(0, x0));
        const float vx = (xs >= 0.0f && xs <= (float)(W - 1)) ? 1.0f : 0.0f;
        const int xb = min(x0, W - 2);         // float2 base column
        const bool edge = (x0 != xb);
        const float a = edge ? 0.0f : vx * (1.0f - lx);
        const float b = edge ? vx : vx * lx;

        // x window endpoints (tx=0,1), identical on every thread
        const float xsA = bx1 * (float)(W - 1);
        int xA = (int)floorf(xsA); xA = min(W - 1, max(0, xA));
        const int xbA = min(xA, W - 2);
        const float xsB = bx2 * (float)(W - 1);
        int xB = (int)floorf(xsB); xB = min(W - 1, max(0, xB));
        const int xbB = min(xB, W - 2);
        const int xb0  = xbA & ~3;                // 16B-aligned window start
        const int need = xbB + 2 - xb0;           // cols needed from xb0
        const int sa4  = (need + 3) >> 2;         // float4s/row

        s_off0[tid] = y0 * W + xb;
        s_off1[tid] = y1 * W + xb;
        s_a[tid] = a;
        s_b[tid] = b;
        s_w0[tid] = vy * (1.0f - ly);
        s_w1[tid] = vy * ly;
        s_dx[tid] = xb - xb0;
        if (px == 0) {
            s_rowoff[2 * py]     = y0 * W;
            s_rowoff[2 * py + 1] = y1 * W;
        }
        if (tid == 0) {
            s_HW   = H * W;
            s_fmap = (level == 2) ? p2 : (level == 3) ? p3 : (level == 4) ? p4 : p5;
            s_xb0  = xb0;
            s_sel  = (need <= 28) ? (sa4 | 1) : 0;   // 1/3/5/7 fast, 0 fallback
        }
    }
    __syncthreads();                 // the only block-wide barrier (1 wave)

    const int HW = s_HW;
    const float* __restrict__ lvl = s_fmap;
    const int lane = tid;            // 64-thread block = one wave
    const int sel  = s_sel;
    const int chw  = sixteenth * WCH;

    if (sel) {
        const unsigned cb0 = (unsigned)chw * (unsigned)HW;
        const unsigned lim = (unsigned)(NCH * HW - 4);
        float* buf0 = &s_stage[0][0];
        float* buf1 = &s_stage[1][0];
        float* __restrict__ opw =
            out + (size_t)n * ELEMS_PER_BOX + (size_t)chw * 49;

        if (sel == 5)
            fast_steps<5>(lvl, opw, buf0, buf1, lane, HW, cb0, lim, s_xb0,
                          s_rowoff, s_dx, s_a, s_b, s_w0, s_w1);
        else if (sel == 7)
            fast_steps<7>(lvl, opw, buf0, buf1, lane, HW, cb0, lim, s_xb0,
                          s_rowoff, s_dx, s_a, s_b, s_w0, s_w1);
        else if (sel == 3)
            fast_steps<3>(lvl, opw, buf0, buf1, lane, HW, cb0, lim, s_xb0,
                          s_rowoff, s_dx, s_a, s_b, s_w0, s_w1);
        else
            fast_steps<1>(lvl, opw, buf0, buf1, lane, HW, cb0, lim, s_xb0,
                          s_rowoff, s_dx, s_a, s_b, s_w0, s_w1);
    } else {
        // wide-x-window fallback: R3-style float2 gathers, 64 lanes,
        // 784 outputs = 12 full rounds of 64 + 16-lane tail (o = 768+lane).
        const float* __restrict__ fbase = lvl + (size_t)chw * HW;
        float* __restrict__ op =
            out + (size_t)n * ELEMS_PER_BOX + (size_t)chw * 49;

        int c  = lane / 49;              // 0..1
        int pp = lane - 49 * c;
#pragma unroll
        for (int g = 0; g < 13; ++g) {
            const int o = g * 64 + lane;
            if (g < 12 || lane < BLKOUT - 768) {
                const float* pl = fbase + (size_t)c * HW;
                const f2 q0 = *(const f2*)(pl + s_off0[pp]);
                const f2 q1 = *(const f2*)(pl + s_off1[pp]);
                const float aa = s_a[pp], bb = s_b[pp];
                const float r0 = q0.x * aa + q0.y * bb;
                const float r1 = q1.x * aa + q1.y * bb;
                op[o] = r0 * s_w0[pp] + r1 * s_w1[pp];
            }
            // advance flat index by 64: 64 = 1*49 + 15
            c += 1; pp += 15;
            if (pp >= 49) { pp -= 49; c += 1; }
        }
    }
}

extern "C" void kernel_launch(void* const* d_in, const int* in_sizes, int n_in,
                              void* d_out, int out_size, void* d_ws, size_t ws_size,
                              hipStream_t stream) {
    const float* boxes = (const float*)d_in[0];
    const float* p2    = (const float*)d_in[1];
    const float* p3    = (const float*)d_in[2];
    const float* p4    = (const float*)d_in[3];
    const float* p5    = (const float*)d_in[4];
    float* out = (float*)d_out;
    const int N = in_sizes[0] / 4;

    roi_align_kernel<<<N * 16, 64, 0, stream>>>(boxes, p2, p3, p4, p5, out, N);
}

// Round 11
// 148.060 us; speedup vs baseline: 1.0087x; 1.0087x over previous
//
#include <hip/hip_runtime.h>

// pyramid_roi_align (Mask R-CNN), MI355X.
// R11b: verbatim resubmit of R11 (round 10 died at container acquire twice --
// same infra signature as rounds 2 & 5, whose resubmits then ran fine; audit
// found no fault path: no loop barriers, all addresses in-bounds, f4 loads
// aligned(4), no dynamic-index register arrays).
// Design: staging family (R6-R10) converges at 44-48us and never beats R3's
// 40.8 -> it traded occupancy (5-10 waves/CU, LDS-capped) for lane count, but
// the kernel is HBM-latency exposed (harness fills flush L3 between iters)
// and R3's 32 waves/CU was the actual win. R11 keeps R3's high-occupancy
// no-barrier structure and cuts LANE COUNT instead: adjacent-px cell pairs
// share one unaligned float4 per row (4 taps in one load) whenever
// x0(px+1)-x0(px) <= 2 (x-step = boxw/6 ~ 2.3); per-unit f2 fallback when
// wider. Lane-loads/ch = 98-42v <= R3's 98 strictly. Weights precomputed as
// 4-vectors per unit (dot == R3 math). ~4KB LDS, no main-loop barriers.

#define POOL 7
#define NCH  256
#define ELEMS_PER_BOX (NCH * POOL * POOL)   // 12544
#define UNITS 28                            // 7py x (3 px-pairs + 1 single)
#define BOX_UNITS (NCH * UNITS)             // 7168
#define CHUNKS 7
#define CHUNK_UNITS (BOX_UNITS / CHUNKS)    // 1024
#define ITERS (CHUNK_UNITS / 256)           // 4

typedef float f2  __attribute__((ext_vector_type(2), aligned(4)));
typedef float f4u __attribute__((ext_vector_type(4), aligned(4)));

__global__ __launch_bounds__(256, 4) void roi_align_kernel(
    const float* __restrict__ boxes,
    const float* __restrict__ p2, const float* __restrict__ p3,
    const float* __restrict__ p4, const float* __restrict__ p5,
    float* __restrict__ out, int N)
{
    const int bid   = blockIdx.x;
    const int n     = bid % N;      // box; chunks N apart (1000%8==0 -> same XCD)
    const int chunk = bid / N;      // unit-range [1024*chunk, +1024)

    // cell tables (phase 1)
    __shared__ float s_a[49], s_b[49], s_w0[49], s_w1[49];
    __shared__ int   s_x0[49];                    // clamped f2 base col (xb)
    __shared__ int   s_r0[7], s_r1[7];            // y0*W, y1*W per py
    __shared__ int   s_HW, s_W;
    __shared__ const float* s_fmap;
    // unit tables (phase 2)
    __shared__ int    s_uoff0[28], s_uoff1[28];   // f4 row bases (y*W + xq)
    __shared__ int    s_woff0[28], s_woff1[28];   // wide f2 bases, -1 if not
    __shared__ int    s_meta[28];                 // pA | (pair<<8)
    __shared__ float  s_uw0[28], s_uw1[28];       // vy-folded y-weights
    __shared__ float  s_aB[28], s_bB[28];         // wide-path B x-weights
    __shared__ float4 s_wA4[28], s_wB4[28];       // f4 weight vectors

    const int tid = threadIdx.x;

    if (tid < 49) {
        const float by1 = boxes[4 * n + 0];
        const float bx1 = boxes[4 * n + 1];
        const float by2 = boxes[4 * n + 2];
        const float bx2 = boxes[4 * n + 3];
        const float h = by2 - by1;
        const float w = bx2 - bx1;
        float rl = 4.0f + log2f(sqrtf(h * w) / 0.21875f);
        int level = (int)rintf(rl);            // round-half-even = jnp.round
        level = min(5, max(2, level));
        const int H = 256 >> (level - 2);
        const int W = H;
        const int py = tid / 7;
        const int px = tid - 7 * py;

        // y interp
        const float ty = (float)py / 6.0f;
        const float ys = (by1 + ty * (by2 - by1)) * (float)(H - 1);
        const float yf = floorf(ys);
        const float ly = ys - yf;
        int y0 = (int)yf; y0 = min(H - 1, max(0, y0));
        const int y1 = min(H - 1, y0 + 1);
        const float vy = (ys >= 0.0f && ys <= (float)(H - 1)) ? 1.0f : 0.0f;

        // x interp
        const float tx = (float)px / 6.0f;
        const float xs = (bx1 + tx * (bx2 - bx1)) * (float)(W - 1);
        const float xf = floorf(xs);
        const float lx = xs - xf;
        int x0 = (int)xf; x0 = min(W - 1, max(0, x0));
        const float vx = (xs >= 0.0f && xs <= (float)(W - 1)) ? 1.0f : 0.0f;
        const int xb = min(x0, W - 2);         // f2 base column
        // normal: taps at xb,xb+1 with (a,b) = vx*(wx0,wx1)
        // edge (x0==W-1): taps xb=W-2,W-1=x0 -> a=0, b=vx*(wx0+wx1)=vx
        const bool edge = (x0 != xb);
        const float a = edge ? 0.0f : vx * (1.0f - lx);
        const float b = edge ? vx : vx * lx;

        s_x0[tid] = xb;
        s_a[tid]  = a;
        s_b[tid]  = b;
        s_w0[tid] = vy * (1.0f - ly);
        s_w1[tid] = vy * ly;
        if (px == 0) { s_r0[py] = y0 * W; s_r1[py] = y1 * W; }
        if (tid == 0) {
            s_HW = H * W;
            s_W  = W;
            s_fmap = (level == 2) ? p2 : (level == 3) ? p3 : (level == 4) ? p4 : p5;
        }
    }
    __syncthreads();

    if (tid < 28) {
        const int W  = s_W;
        const int py = tid >> 2;
        const int xu = tid & 3;
        const int pA = py * 7 + 2 * xu;        // xu==3 -> single cell px=6
        const bool pair = (xu < 3);
        const int x0A = s_x0[pA];
        const int x0B = pair ? s_x0[pA + 1] : x0A;
        const int xq  = min(x0A, W - 4);       // f4 base (always in-row)
        const int dA  = x0A - xq;              // 0..2
        const int dB  = x0B - xq;
        const bool wide = pair && (dB > 2);    // B taps don't fit the f4
        const float aA = s_a[pA], bA = s_b[pA];
        const float aB = pair ? s_a[pA + 1] : 0.0f;
        const float bB = pair ? s_b[pA + 1] : 0.0f;

        float4 wa, wb;
        wa.x = (dA == 0) ? aA : 0.0f;
        wa.y = (dA == 0) ? bA : ((dA == 1) ? aA : 0.0f);
        wa.z = (dA == 1) ? bA : ((dA == 2) ? aA : 0.0f);
        wa.w = (dA == 2) ? bA : 0.0f;
        const bool nb = pair && !wide;
        wb.x = (nb && dB == 0) ? aB : 0.0f;
        wb.y = nb ? ((dB == 0) ? bB : ((dB == 1) ? aB : 0.0f)) : 0.0f;
        wb.z = nb ? ((dB == 1) ? bB : ((dB == 2) ? aB : 0.0f)) : 0.0f;
        wb.w = (nb && dB == 2) ? bB : 0.0f;

        s_uoff0[tid] = s_r0[py] + xq;
        s_uoff1[tid] = s_r1[py] + xq;
        s_woff0[tid] = wide ? (s_r0[py] + x0B) : -1;
        s_woff1[tid] = wide ? (s_r1[py] + x0B) : -1;
        s_meta[tid]  = pA | (pair ? 0x100 : 0);
        s_uw0[tid] = s_w0[pA];                 // A,B share py -> same y-weights
        s_uw1[tid] = s_w1[pA];
        s_aB[tid] = aB;
        s_bB[tid] = bB;
        s_wA4[tid] = wa;
        s_wB4[tid] = wb;
    }
    __syncthreads();                 // last barrier; main loop barrier-free

    const int HW = s_HW;
    const float* __restrict__ lvl = s_fmap;
    float* __restrict__ obase = out + (size_t)n * ELEMS_PER_BOX;

    const int flat0 = chunk * CHUNK_UNITS + tid;
    const int c0 = flat0 / 28;       // one runtime div
    const int u0 = flat0 - 28 * c0;

    // phase 1: issue all gathers (f4 per row; wide units add 2 f2, predicated)
    f4u q0[ITERS], q1[ITERS];
    f2  e0[ITERS], e1[ITERS];
    int cc[ITERS], uu[ITERS];
    {
        int c_ = c0, u_ = u0;
#pragma unroll
        for (int k = 0; k < ITERS; ++k) {
            cc[k] = c_; uu[k] = u_;
            const float* pl = lvl + (size_t)c_ * HW;
            q0[k] = *(const f4u*)(pl + s_uoff0[u_]);
            q1[k] = *(const f4u*)(pl + s_uoff1[u_]);
            const int wo0 = s_woff0[u_];
            if (wo0 >= 0) {
                e0[k] = *(const f2*)(pl + wo0);
                e1[k] = *(const f2*)(pl + s_woff1[u_]);
            }
            // advance by 256 units: 256 = 9*28 + 4
            c_ += 9; u_ += 4;
            if (u_ >= 28) { u_ -= 28; c_ += 1; }
        }
    }

    // phase 2: combine + store
#pragma unroll
    for (int k = 0; k < ITERS; ++k) {
        const int u_ = uu[k];
        const float w0u = s_uw0[u_], w1u = s_uw1[u_];
        const float4 wa = s_wA4[u_];
        const float r0 = q0[k].x * wa.x + q0[k].y * wa.y +
                         q0[k].z * wa.z + q0[k].w * wa.w;
        const float r1 = q1[k].x * wa.x + q1[k].y * wa.y +
                         q1[k].z * wa.z + q1[k].w * wa.w;
        const int meta = s_meta[u_];
        float* op = obase + cc[k] * 49 + (meta & 0xff);
        op[0] = r0 * w0u + r1 * w1u;
        if (meta & 0x100) {
            float oB;
            if (s_woff0[u_] >= 0) {            // wide pair: dedicated f2 taps
                const float aB = s_aB[u_], bB = s_bB[u_];
                oB = (e0[k].x * aB + e0[k].y * bB) * w0u +
                     (e1[k].x * aB + e1[k].y * bB) * w1u;
            } else {                           // shared-f4 pair
                const float4 wb = s_wB4[u_];
                const float s0 = q0[k].x * wb.x + q0[k].y * wb.y +
                                 q0[k].z * wb.z + q0[k].w * wb.w;
                const float s1 = q1[k].x * wb.x + q1[k].y * wb.y +
                                 q1[k].z * wb.z + q1[k].w * wb.w;
                oB = s0 * w0u + s1 * w1u;
            }
            op[1] = oB;
        }
    }
}

extern "C" void kernel_launch(void* const* d_in, const int* in_sizes, int n_in,
                              void* d_out, int out_size, void* d_ws, size_t ws_size,
                              hipStream_t stream) {
    const float* boxes = (const float*)d_in[0];
    const float* p2    = (const float*)d_in[1];
    const float* p3    = (const float*)d_in[2];
    const float* p4    = (const float*)d_in[3];
    const float* p5    = (const float*)d_in[4];
    float* out = (float*)d_out;
    const int N = in_sizes[0] / 4;

    roi_align_kernel<<<N * CHUNKS, 256, 0, stream>>>(boxes, p2, p3, p4, p5, out, N);
}